// Round 7
// baseline (108.714 us; speedup 1.0000x reference)
//
#include <hip/hip_runtime.h>

#define NSTEP 39                 // K = 39*32 = 1248 slots
#define NCOL  (NSTEP * 8)        // 312 feature columns; packed in PAIRS (156 packs)

typedef _Float16 half8   __attribute__((ext_vector_type(8)));
typedef __fp16   f16x2   __attribute__((ext_vector_type(2)));
typedef __fp16   f16x4   __attribute__((ext_vector_type(4)));
typedef __fp16   f16x8   __attribute__((ext_vector_type(8)));
typedef float    float4v __attribute__((ext_vector_type(4)));

// Column table, ordered so columns (2j, 2j+1) form a v_pk_mul_f16-friendly
// pair (same mode, same o). Per column c, 4 features (q = 0..3):
//   mode 3: x_a * x_b * x_{o+q}  (valid iff o+q >= a; a <= o+3)
//   mode 2: x_a * x_{o+q}        (valid iff o+q <= a; a >= o)
//   mode 1: x_{o+q}              (always valid; +identity folded in W)
//   mode 4: 1.0                  (valid iff q == 0)
//   mode 0: pad (W row zero)
// Invalid slots are zeroed on the W side; A side computes finite garbage * 0.
struct Cols { short mode[NCOL]; short a[NCOL]; short b[NCOL]; short o[NCOL]; };
static constexpr Cols mk_cols() {
  Cols c{};
  int k = 0;
  // specials: 4x deg-1, 1x const, 1x pad  (3 packs)
  for (int o = 0; o < 16; o += 4) { c.mode[k] = 1; c.o[k] = (short)o; ++k; }
  c.mode[k] = 4; ++k;
  c.mode[k] = 0; ++k;
  // deg-2: for o, a = o..15 -> pairs (a, a+1) with a-o even, A-pack = x2[a/2]
  for (int o = 0; o < 16; o += 4)
    for (int a = o; a < 16; ++a) { c.mode[k] = 2; c.a[k] = (short)a; c.o[k] = (short)o; ++k; }
  // deg-3: per o, regular pairs (a,b),(a,b+1) b even, then leftover (a,a) evens
  for (int o = 0; o < 16; o += 4) {
    const int amax = (o + 3 < 15) ? o + 3 : 15;
    for (int a = 0; a <= amax; ++a)
      for (int b = 0; b + 1 <= a; b += 2) {
        c.mode[k] = 3; c.a[k] = (short)a; c.b[k] = (short)b;     c.o[k] = (short)o; ++k;
        c.mode[k] = 3; c.a[k] = (short)a; c.b[k] = (short)(b+1); c.o[k] = (short)o; ++k;
      }
    for (int a = 0; a <= amax; a += 2) {
      c.mode[k] = 3; c.a[k] = (short)a; c.b[k] = (short)a; c.o[k] = (short)o; ++k;
    }
  }
  for (; k < NCOL; ++k) c.mode[k] = 0;    // pad cols
  return c;
}
static constexpr Cols COLS = mk_cols();

// ---- Pre-kernel: f16 W fragments (permutation + validity zeroing + identity
// fold) into d_ws. Entry e = (step, q, n): 8 halfs = B[k=step*32+q*8+j][n].
__global__ void build_wfrag(const float* __restrict__ W, _Float16* __restrict__ Wp) {
  const int e = blockIdx.x * 256 + threadIdx.x;
  if (e >= NSTEP * 64) return;
  const int step = e >> 6;
  const int q    = (e >> 4) & 3;
  const int n    = e & 15;
  half8 hv;
  #pragma unroll
  for (int j = 0; j < 8; ++j) {
    const int c = step * 8 + j;
    const int mode = COLS.mode[c], a = COLS.a[c], b = COLS.b[c], o = COLS.o[c];
    float v = 0.0f;
    if (mode == 3) {
      const int i = o + q;                      // i <= 15 guaranteed
      if (i >= a) v = W[(153 + i * (i + 1) * (i + 2) / 6 + a * (a + 1) / 2 + b) * 16 + n];
    } else if (mode == 2) {
      const int bb = o + q;
      if (bb <= a) v = W[(17 + a * (a + 1) / 2 + bb) * 16 + n];
    } else if (mode == 1) {
      const int i = o + q;
      v = W[(1 + i) * 16 + n];
      if (i == n) v += 1.0f;                    // fold residual: out = x + poly@W
    } else if (mode == 4) {
      if (q == 0) v = W[n];
    }
    hv[j] = (_Float16)v;
  }
  *(half8*)(Wp + e * 8) = hv;
}

// Packed pair of features (cols C, C+1), C even. x2[r] = (x_{2r}, x_{2r+1});
// w2[j] = (x_{4j+q}, x_{4j+q}) broadcast.
template<int C>
__device__ __forceinline__ f16x2 colpair(const f16x2 (&x2)[8], const f16x2 (&w2)[4]) {
  constexpr int m0 = COLS.mode[C], m1 = COLS.mode[C + 1];
  if constexpr (m0 == 3 && COLS.a[C] == COLS.b[C]) {
    // leftover pair: (x_{a1}^2, x_{a2}^2) * w
    constexpr int a1 = COLS.a[C], a2 = COLS.a[C + 1];
    const f16x2 s = __builtin_shufflevector(x2[a1 / 2], x2[a2 / 2], a1 % 2, 2 + a2 % 2);
    return (s * s) * w2[COLS.o[C] >> 2];
  } else if constexpr (m0 == 3) {
    // regular pair: x_a * (x_b, x_{b+1}) * w   (b even)
    constexpr int a = COLS.a[C], b = COLS.b[C];
    const f16x2 xa = __builtin_shufflevector(x2[a / 2], x2[a / 2], a % 2, a % 2);
    return (xa * x2[b / 2]) * w2[COLS.o[C] >> 2];
  } else if constexpr (m0 == 2) {
    // pair: (x_a, x_{a+1}) * w   (a-o even, so x2[a/2] is the pack)
    return x2[COLS.a[C] / 2] * w2[COLS.o[C] >> 2];
  } else if constexpr (m0 == 1 && m1 == 1) {
    // (w_{o1+q}, w_{o2+q})
    return __builtin_shufflevector(w2[COLS.o[C] >> 2], w2[COLS.o[C + 1] >> 2], 0, 2);
  } else if constexpr (m0 == 4) {
    return (f16x2){(__fp16)1.0f, (__fp16)0.0f};
  } else {
    return (f16x2){(__fp16)0.0f, (__fp16)0.0f};
  }
}

template<int Q, int T, int J>
__device__ __forceinline__ void setw2_one(const f16x2 (&x2)[2][8], f16x2 (&w2)[2][4]) {
  constexpr int idx = 4 * J + Q;
  w2[T][J] = __builtin_shufflevector(x2[T][idx / 2], x2[T][idx / 2], idx % 2, idx % 2);
}

template<int Q>
__device__ __forceinline__ void setw2(const f16x2 (&x2)[2][8], f16x2 (&w2)[2][4]) {
  setw2_one<Q, 0, 0>(x2, w2); setw2_one<Q, 0, 1>(x2, w2);
  setw2_one<Q, 0, 2>(x2, w2); setw2_one<Q, 0, 3>(x2, w2);
  setw2_one<Q, 1, 0>(x2, w2); setw2_one<Q, 1, 1>(x2, w2);
  setw2_one<Q, 1, 2>(x2, w2); setw2_one<Q, 1, 3>(x2, w2);
}

template<int S>
__device__ __forceinline__ void steps(const _Float16* __restrict__ wfq,
                                      const f16x2 (&x2)[2][8], const f16x2 (&w2)[2][4],
                                      float4v (&acc)[2]) {
  if constexpr (S < NSTEP) {
    const half8 bf = *(const half8*)(wfq + S * 512);     // ds_read_b128, imm offset
    #pragma unroll
    for (int t = 0; t < 2; ++t) {
      const f16x2 p01 = colpair<S * 8 + 0>(x2[t], w2[t]);
      const f16x2 p23 = colpair<S * 8 + 2>(x2[t], w2[t]);
      const f16x2 p45 = colpair<S * 8 + 4>(x2[t], w2[t]);
      const f16x2 p67 = colpair<S * 8 + 6>(x2[t], w2[t]);
      const f16x4 lo = __builtin_shufflevector(p01, p23, 0, 1, 2, 3);
      const f16x4 hi = __builtin_shufflevector(p45, p67, 0, 1, 2, 3);
      const f16x8 a8 = __builtin_shufflevector(lo, hi, 0, 1, 2, 3, 4, 5, 6, 7);
      const half8 af = __builtin_bit_cast(half8, a8);
      acc[t] = __builtin_amdgcn_mfma_f32_16x16x32_f16(af, bf, acc[t], 0, 0, 0);
    }
    steps<S + 1>(wfq, x2, w2, acc);
  }
}

// Block = 512 threads = 8 waves; each wave owns 32 rows (2 m-tiles of 16).
// 8192 waves total; VGPR<=64 + LDS 39.9KB*4 = 156KB -> 32 waves/CU, ONE pass.
__global__ __launch_bounds__(512, 8)
void taylor_fwd(const float* __restrict__ X, const _Float16* __restrict__ Wp,
                float* __restrict__ O) {
  __shared__ _Float16 wfrag[NSTEP * 512];          // 39936 B
  const int tid  = threadIdx.x;
  const int lane = tid & 63;
  const int wv   = tid >> 6;
  const int m    = lane & 15;
  const int q    = lane >> 4;

  // stage W fragments (coalesced float4 copy from d_ws)
  {
    float4v* dst = (float4v*)wfrag;
    const float4v* src = (const float4v*)Wp;
    #pragma unroll
    for (int i = 0; i < 5; ++i) {
      const int idx = tid + i * 512;
      if (idx < NSTEP * 64) dst[idx] = src[idx];
    }
  }
  __syncthreads();

  // load 2 rows of x, convert to packed f16 (x2[t][r] = (x_{2r}, x_{2r+1}))
  const int rb = blockIdx.x * 256 + wv * 32;
  f16x2 x2[2][8];
  #pragma unroll
  for (int t = 0; t < 2; ++t) {
    const float4v* xp = (const float4v*)(X + (size_t)(rb + t * 16 + m) * 16);
    #pragma unroll
    for (int c4 = 0; c4 < 4; ++c4) {
      const float4v v = xp[c4];
      x2[t][c4 * 2 + 0] = __builtin_amdgcn_cvt_pkrtz(v[0], v[1]);
      x2[t][c4 * 2 + 1] = __builtin_amdgcn_cvt_pkrtz(v[2], v[3]);
    }
  }

  // broadcast packs of the q-shifted view: w2[j] = (x_{4j+q}, x_{4j+q})
  f16x2 w2[2][4];
  if (q == 0)      setw2<0>(x2, w2);
  else if (q == 1) setw2<1>(x2, w2);
  else if (q == 2) setw2<2>(x2, w2);
  else             setw2<3>(x2, w2);

  float4v acc[2];
  acc[0] = (float4v){0.f, 0.f, 0.f, 0.f};
  acc[1] = (float4v){0.f, 0.f, 0.f, 0.f};

  const _Float16* wfq = wfrag + (q * 16 + m) * 8;   // + S*512 per step
  steps<0>(wfq, x2, w2, acc);

  // Epilogue: C/D layout col = lane&15, row = q*4 + reg
  #pragma unroll
  for (int t = 0; t < 2; ++t) {
    #pragma unroll
    for (int r = 0; r < 4; ++r) {
      const int row = rb + t * 16 + q * 4 + r;
      O[(size_t)row * 16 + m] = acc[t][r];
    }
  }
}

extern "C" void kernel_launch(void* const* d_in, const int* in_sizes, int n_in,
                              void* d_out, int out_size, void* d_ws, size_t ws_size,
                              hipStream_t stream) {
  const float* X = (const float*)d_in[0];
  const float* W = (const float*)d_in[1];
  float*       O = (float*)d_out;
  _Float16*    Wp = (_Float16*)d_ws;               // NSTEP*64*16 B = 39936 B
  const int batch = in_sizes[0] / 16;              // 262144
  const int grid  = batch / 256;                   // 1024 blocks x 256 rows

  build_wfrag<<<(NSTEP * 64 + 255) / 256, 256, 0, stream>>>(W, Wp);
  taylor_fwd<<<grid, 512, 0, stream>>>(X, Wp, O);
}

// Round 8
// 86.491 us; speedup vs baseline: 1.2569x; 1.2569x over previous
//
#include <hip/hip_runtime.h>

#define NSTEP 39                 // K = 39*32 = 1248 slots
#define NCOL  (NSTEP * 8)        // 312 feature columns; packed in PAIRS (156 packs)

typedef _Float16 half8   __attribute__((ext_vector_type(8)));
typedef __fp16   f16x2   __attribute__((ext_vector_type(2)));
typedef __fp16   f16x4   __attribute__((ext_vector_type(4)));
typedef __fp16   f16x8   __attribute__((ext_vector_type(8)));
typedef float    float4v __attribute__((ext_vector_type(4)));

// Column table, ordered so columns (2j, 2j+1) form a v_pk_mul_f16-friendly
// pair (same mode, same o). Per column c, 4 features (q = 0..3):
//   mode 3: x_a * x_b * x_{o+q}  (valid iff o+q >= a; a <= o+3)
//   mode 2: x_a * x_{o+q}        (valid iff o+q <= a; a >= o)
//   mode 1: x_{o+q}              (always valid; +identity folded in W)
//   mode 4: 1.0                  (valid iff q == 0)
//   mode 0: pad (W row zero)
// Invalid slots are zeroed on the W side; A side computes finite garbage * 0.
struct Cols { short mode[NCOL]; short a[NCOL]; short b[NCOL]; short o[NCOL]; };
static constexpr Cols mk_cols() {
  Cols c{};
  int k = 0;
  // specials: 4x deg-1, 1x const, 1x pad  (3 packs)
  for (int o = 0; o < 16; o += 4) { c.mode[k] = 1; c.o[k] = (short)o; ++k; }
  c.mode[k] = 4; ++k;
  c.mode[k] = 0; ++k;
  // deg-2: for o, a = o..15 -> pairs (a, a+1) with a even, A-pack = x2[a/2]
  for (int o = 0; o < 16; o += 4)
    for (int a = o; a < 16; ++a) { c.mode[k] = 2; c.a[k] = (short)a; c.o[k] = (short)o; ++k; }
  // deg-3: per o, regular pairs (a,b),(a,b+1) b even, then leftover (a,a) evens
  for (int o = 0; o < 16; o += 4) {
    const int amax = (o + 3 < 15) ? o + 3 : 15;
    for (int a = 0; a <= amax; ++a)
      for (int b = 0; b + 1 <= a; b += 2) {
        c.mode[k] = 3; c.a[k] = (short)a; c.b[k] = (short)b;     c.o[k] = (short)o; ++k;
        c.mode[k] = 3; c.a[k] = (short)a; c.b[k] = (short)(b+1); c.o[k] = (short)o; ++k;
      }
    for (int a = 0; a <= amax; a += 2) {
      c.mode[k] = 3; c.a[k] = (short)a; c.b[k] = (short)a; c.o[k] = (short)o; ++k;
    }
  }
  for (; k < NCOL; ++k) c.mode[k] = 0;    // pad cols
  return c;
}
static constexpr Cols COLS = mk_cols();

// ---- Pre-kernel: f16 W fragments (permutation + validity zeroing + identity
// fold) into d_ws. Entry e = (step, q, n): 8 halfs = B[k=step*32+q*8+j][n].
__global__ void build_wfrag(const float* __restrict__ W, _Float16* __restrict__ Wp) {
  const int e = blockIdx.x * 256 + threadIdx.x;
  if (e >= NSTEP * 64) return;
  const int step = e >> 6;
  const int q    = (e >> 4) & 3;
  const int n    = e & 15;
  half8 hv;
  #pragma unroll
  for (int j = 0; j < 8; ++j) {
    const int c = step * 8 + j;
    const int mode = COLS.mode[c], a = COLS.a[c], b = COLS.b[c], o = COLS.o[c];
    float v = 0.0f;
    if (mode == 3) {
      const int i = o + q;                      // i <= 15 guaranteed
      if (i >= a) v = W[(153 + i * (i + 1) * (i + 2) / 6 + a * (a + 1) / 2 + b) * 16 + n];
    } else if (mode == 2) {
      const int bb = o + q;
      if (bb <= a) v = W[(17 + a * (a + 1) / 2 + bb) * 16 + n];
    } else if (mode == 1) {
      const int i = o + q;
      v = W[(1 + i) * 16 + n];
      if (i == n) v += 1.0f;                    // fold residual: out = x + poly@W
    } else if (mode == 4) {
      if (q == 0) v = W[n];
    }
    hv[j] = (_Float16)v;
  }
  *(half8*)(Wp + e * 8) = hv;
}

// Packed pair of features (cols C, C+1), C even. x2[r] = (x_{2r}, x_{2r+1});
// w2[j] = (x_{4j+q}, x_{4j+q}) broadcast.
template<int C>
__device__ __forceinline__ f16x2 colpair(const f16x2 (&x2)[8], const f16x2 (&w2)[4]) {
  constexpr int m0 = COLS.mode[C], m1 = COLS.mode[C + 1];
  if constexpr (m0 == 3 && COLS.a[C] == COLS.b[C]) {
    // leftover pair: (x_{a1}^2, x_{a2}^2) * w
    constexpr int a1 = COLS.a[C], a2 = COLS.a[C + 1];
    const f16x2 s = __builtin_shufflevector(x2[a1 / 2], x2[a2 / 2], a1 % 2, 2 + a2 % 2);
    return (s * s) * w2[COLS.o[C] >> 2];
  } else if constexpr (m0 == 3) {
    // regular pair: x_a * (x_b, x_{b+1}) * w   (b even; xa broadcast = op_sel)
    constexpr int a = COLS.a[C], b = COLS.b[C];
    const f16x2 xa = __builtin_shufflevector(x2[a / 2], x2[a / 2], a % 2, a % 2);
    return (xa * x2[b / 2]) * w2[COLS.o[C] >> 2];
  } else if constexpr (m0 == 2) {
    // pair: (x_a, x_{a+1}) * w   (a even, so x2[a/2] is the pack)
    return x2[COLS.a[C] / 2] * w2[COLS.o[C] >> 2];
  } else if constexpr (m0 == 1 && m1 == 1) {
    // (w_{o1+q}, w_{o2+q})
    return __builtin_shufflevector(w2[COLS.o[C] >> 2], w2[COLS.o[C + 1] >> 2], 0, 2);
  } else if constexpr (m0 == 4) {
    return (f16x2){(__fp16)1.0f, (__fp16)0.0f};
  } else {
    return (f16x2){(__fp16)0.0f, (__fp16)0.0f};
  }
}

template<int Q, int J>
__device__ __forceinline__ void setw2_one(const f16x2 (&x2)[8], f16x2 (&w2)[4]) {
  constexpr int idx = 4 * J + Q;
  w2[J] = __builtin_shufflevector(x2[idx / 2], x2[idx / 2], idx % 2, idx % 2);
}

template<int Q>
__device__ __forceinline__ void setw2(const f16x2 (&x2)[8], f16x2 (&w2)[4]) {
  setw2_one<Q, 0>(x2, w2); setw2_one<Q, 1>(x2, w2);
  setw2_one<Q, 2>(x2, w2); setw2_one<Q, 3>(x2, w2);
}

template<int S>
__device__ __forceinline__ void steps(const _Float16* __restrict__ wfq,
                                      const f16x2 (&x2)[8], const f16x2 (&w2)[4],
                                      float4v& acc) {
  if constexpr (S < NSTEP) {
    const half8 bf = *(const half8*)(wfq + S * 512);     // ds_read_b128, imm offset
    const f16x2 p01 = colpair<S * 8 + 0>(x2, w2);
    const f16x2 p23 = colpair<S * 8 + 2>(x2, w2);
    const f16x2 p45 = colpair<S * 8 + 4>(x2, w2);
    const f16x2 p67 = colpair<S * 8 + 6>(x2, w2);
    const f16x4 lo = __builtin_shufflevector(p01, p23, 0, 1, 2, 3);
    const f16x4 hi = __builtin_shufflevector(p45, p67, 0, 1, 2, 3);
    const f16x8 a8 = __builtin_shufflevector(lo, hi, 0, 1, 2, 3, 4, 5, 6, 7);
    const half8 af = __builtin_bit_cast(half8, a8);
    acc = __builtin_amdgcn_mfma_f32_16x16x32_f16(af, bf, acc, 0, 0, 0);
    steps<S + 1>(wfq, x2, w2, acc);
  }
}

// Block = 512 threads = 8 waves; each wave owns ONE 16-row m-tile (small live
// state => ~40 VGPR, no spill at the 64-reg/8-wave budget). 2048 blocks,
// 4 blocks/CU (LDS 156KB, 2048 threads) = 32 waves/CU = HW max, 2 full passes.
__global__ __launch_bounds__(512, 8)
void taylor_fwd(const float* __restrict__ X, const _Float16* __restrict__ Wp,
                float* __restrict__ O) {
  __shared__ _Float16 wfrag[NSTEP * 512];          // 39936 B
  const int tid  = threadIdx.x;
  const int lane = tid & 63;
  const int wv   = tid >> 6;
  const int m    = lane & 15;
  const int q    = lane >> 4;

  // stage W fragments (coalesced float4 copy from d_ws)
  {
    float4v* dst = (float4v*)wfrag;
    const float4v* src = (const float4v*)Wp;
    #pragma unroll
    for (int i = 0; i < 5; ++i) {
      const int idx = tid + i * 512;
      if (idx < NSTEP * 64) dst[idx] = src[idx];
    }
  }
  __syncthreads();

  // load my row of x, convert to packed f16 (x2[r] = (x_{2r}, x_{2r+1}))
  const int rb = blockIdx.x * 128 + wv * 16;
  f16x2 x2[8];
  {
    const float4v* xp = (const float4v*)(X + (size_t)(rb + m) * 16);
    #pragma unroll
    for (int c4 = 0; c4 < 4; ++c4) {
      const float4v v = xp[c4];
      x2[c4 * 2 + 0] = __builtin_amdgcn_cvt_pkrtz(v[0], v[1]);
      x2[c4 * 2 + 1] = __builtin_amdgcn_cvt_pkrtz(v[2], v[3]);
    }
  }

  // broadcast packs of the q-shifted view: w2[j] = (x_{4j+q}, x_{4j+q})
  f16x2 w2[4];
  if (q == 0)      setw2<0>(x2, w2);
  else if (q == 1) setw2<1>(x2, w2);
  else if (q == 2) setw2<2>(x2, w2);
  else             setw2<3>(x2, w2);

  float4v acc = (float4v){0.f, 0.f, 0.f, 0.f};

  const _Float16* wfq = wfrag + (q * 16 + m) * 8;   // + S*512 per step
  steps<0>(wfq, x2, w2, acc);

  // Epilogue: C/D layout col(n) = lane&15, row = q*4 + reg
  #pragma unroll
  for (int r = 0; r < 4; ++r) {
    const int row = rb + q * 4 + r;
    O[(size_t)row * 16 + m] = acc[r];
  }
}

extern "C" void kernel_launch(void* const* d_in, const int* in_sizes, int n_in,
                              void* d_out, int out_size, void* d_ws, size_t ws_size,
                              hipStream_t stream) {
  const float* X = (const float*)d_in[0];
  const float* W = (const float*)d_in[1];
  float*       O = (float*)d_out;
  _Float16*    Wp = (_Float16*)d_ws;               // NSTEP*64*16 B = 39936 B
  const int batch = in_sizes[0] / 16;              // 262144
  const int grid  = batch / 128;                   // 2048 blocks x 128 rows

  build_wfrag<<<(NSTEP * 64 + 255) / 256, 256, 0, stream>>>(W, Wp);
  taylor_fwd<<<grid, 512, 0, stream>>>(X, Wp, O);
}